// Round 13
// baseline (110.134 us; speedup 1.0000x reference)
//
#include <hip/hip_runtime.h>
#include <hip/hip_bf16.h>

typedef __attribute__((ext_vector_type(8))) short short8;
typedef __attribute__((ext_vector_type(4))) short short4v;
typedef __attribute__((ext_vector_type(4))) float f32x4;

// ws: A' [8192][128] bf16 (2MB) | B' [8192][128] bf16 (2MB) | WoutT [128][1024] bf16 (256KB)
//   | W12bf [64][256] bf16 (32KB) | O_ws [65536][1024] bf16 (128MB, optional)
#define WS_A   0
#define WS_B   (8192 * 128 * 2)
#define WS_WT  (2 * 8192 * 128 * 2)
#define WS_W12 (WS_WT + 128 * 1024 * 2)
#define WS_O   (WS_W12 + 32768)
#define WS_O_BYTES ((size_t)65536 * 1024 * 2)

static __device__ __forceinline__ short f2bf(float x) {
    __hip_bfloat16 h = __float2bfloat16(x);
    return *reinterpret_cast<short*>(&h);
}

typedef __attribute__((address_space(3))) unsigned int lds_u32;
typedef const __attribute__((address_space(1))) unsigned int glb_u32;
static __device__ __forceinline__ void stage16(const void* g, void* l) {
    __builtin_amdgcn_global_load_lds((glb_u32*)g, (lds_u32*)l, 16, 0, 0);
}

// ---------------- Kernel 0: Wout -> bf16 [z][ck]; W1|W2 -> bf16 [64 c][256 d] ----------------
__global__ __launch_bounds__(256) void k_prep(const float* __restrict__ Wout,
                                              const float* __restrict__ W1,
                                              const float* __restrict__ W2,
                                              __hip_bfloat16* __restrict__ WoutT,
                                              __hip_bfloat16* __restrict__ W12bf) {
    int idx = blockIdx.x * 256 + threadIdx.x;
    if (blockIdx.x < 512) {
        int z = idx >> 10, ck = idx & 1023;
        WoutT[idx] = __float2bfloat16(Wout[ck * 128 + z]);
    } else {
        idx -= 512 * 256;
        int c = idx >> 8, d = idx & 255;
        W12bf[idx] = __float2bfloat16(c < 32 ? W1[d * 32 + c] : W2[d * 32 + (c - 32)]);
    }
}

// ---------------- Kernel 1: LayerNorm + dual projection via MFMA (unchanged) ----------------
__global__ __launch_bounds__(256) void k_lnproj(const float* __restrict__ mm,
                                                const float* __restrict__ gamma,
                                                const float* __restrict__ beta,
                                                const float* __restrict__ b1,
                                                const float* __restrict__ b2,
                                                const __hip_bfloat16* __restrict__ W12bf,
                                                __hip_bfloat16* __restrict__ Ap,
                                                __hip_bfloat16* __restrict__ Bp) {
    __shared__ char sMN[4][8192];
    __shared__ char sW[32768];
    const int t    = threadIdx.x;
    const int lane = t & 63;
    const int wid  = t >> 6;
    const int gw   = blockIdx.x * 4 + wid;
    const int i_   = gw & 255;
    const int sb   = (gw >> 8) * 16;

    #pragma unroll
    for (int it = 0; it < 8; it++) {
        const int idx = it * 256 + t;
        const int row = idx >> 5;
        const int L   = (idx & 31) * 16;
        *(short8*)(sW + row * 512 + (L ^ ((row & 7) << 4))) =
            *(const short8*)((const short*)W12bf + idx * 8);
    }

    float4 g4  = *(const float4*)&gamma[lane * 4];
    float4 be4 = *(const float4*)&beta[lane * 4];
    char* my = sMN[wid];

    #pragma unroll
    for (int rr = 0; rr < 16; rr++) {
        float4 x = *(const float4*)&mm[((size_t)(sb + rr) * 256 + i_) * 256 + lane * 4];
        float s  = x.x + x.y + x.z + x.w;
        float ss = x.x * x.x + x.y * x.y + x.z * x.z + x.w * x.w;
        #pragma unroll
        for (int off = 32; off; off >>= 1) {
            s  += __shfl_xor(s, off);
            ss += __shfl_xor(ss, off);
        }
        float mu  = s * (1.f / 256.f);
        float var = ss * (1.f / 256.f) - mu * mu;
        float rs  = rsqrtf(var + 1e-5f);
        short4v v;
        v.x = f2bf((x.x - mu) * rs * g4.x + be4.x);
        v.y = f2bf((x.y - mu) * rs * g4.y + be4.y);
        v.z = f2bf((x.z - mu) * rs * g4.z + be4.z);
        v.w = f2bf((x.w - mu) * rs * g4.w + be4.w);
        *(short4v*)(my + rr * 512 + ((lane * 8) ^ ((rr & 7) << 4))) = v;
    }
    __syncthreads();

    const int g = lane >> 4, r16 = lane & 15;

    f32x4 acc[4];
    #pragma unroll
    for (int nf = 0; nf < 4; nf++) {
        int col = nf * 16 + r16;
        float bv = (col < 32) ? b1[col] : b2[col - 32];
        acc[nf] = (f32x4){bv, bv, bv, bv};
    }
    #pragma unroll
    for (int ks = 0; ks < 8; ks++) {
        const int L = ks * 64 + g * 16;
        short8 af = *(const short8*)(my + r16 * 512 + (L ^ ((r16 & 7) << 4)));
        #pragma unroll
        for (int nf = 0; nf < 4; nf++) {
            short8 bfv = *(const short8*)(sW + (nf * 16 + r16) * 512 + (L ^ ((r16 & 7) << 4)));
            acc[nf] = __builtin_amdgcn_mfma_f32_16x16x32_bf16(af, bfv, acc[nf], 0, 0, 0);
        }
    }
    #pragma unroll
    for (int nf = 0; nf < 4; nf++) {
        int col = nf * 16 + r16;
        short* Out = (short*)((col < 32) ? Ap : Bp);
        int cr = col & 31;
        short4v v;
        v.x = f2bf(acc[nf][0]); v.y = f2bf(acc[nf][1]);
        v.z = f2bf(acc[nf][2]); v.w = f2bf(acc[nf][3]);
        *(short4v*)&Out[(i_ * 32 + cr) * 128 + sb + g * 4] = v;
    }
}

extern __shared__ char lds[];

// ================= PATH 2, Kernel A: 256x256 O^T GEMM -> O_ws [R=tile*64+p][1024 ck] bf16 ====
__global__ __launch_bounds__(512, 1) void k_gemmA(const __hip_bfloat16* __restrict__ Apb,
                                                  const __hip_bfloat16* __restrict__ Bpb,
                                                  short* __restrict__ gO) {
    const int t = threadIdx.x, lane = t & 63, wid = t >> 6;
    const int g = lane >> 4, r16 = lane & 15;
    const int wr = wid >> 2, wc = wid & 3;
    const int bid = (blockIdx.x & 7) * 128 + (blockIdx.x >> 3);
    const int bi = bid >> 5, bj = bid & 31;

    const short* gA = (const short*)Apb + (size_t)bi * 256 * 128;
    const short* gB = (const short*)Bpb + (size_t)bj * 256 * 128;

    const int srow8 = lane >> 3;
    const int sgran = (lane & 7) ^ srow8;
    #pragma unroll
    for (int kh = 0; kh < 2; kh++) {
        #pragma unroll
        for (int rd = 0; rd < 4; rd++) {
            const int row = rd * 64 + wid * 8 + srow8;
            stage16(gB + row * 128 + kh * 64 + sgran * 8,
                    lds + kh * 65536 + rd * 8192 + wid * 1024);
            stage16(gA + row * 128 + kh * 64 + sgran * 8,
                    lds + kh * 65536 + 32768 + rd * 8192 + wid * 1024);
        }
    }

    asm volatile("s_waitcnt vmcnt(8)" ::: "memory");
    __builtin_amdgcn_s_barrier();

    f32x4 acc[8][4];
    #pragma unroll
    for (int mf = 0; mf < 8; mf++)
        #pragma unroll
        for (int nf = 0; nf < 4; nf++)
            acc[mf][nf] = (f32x4){0.f, 0.f, 0.f, 0.f};

    #pragma unroll
    for (int kh = 0; kh < 2; kh++) {
        if (kh) {
            asm volatile("s_waitcnt vmcnt(0)" ::: "memory");
            __builtin_amdgcn_s_barrier();
        }
        const char* sBb = lds + kh * 65536;
        const char* sAb = lds + kh * 65536 + 32768;
        #pragma unroll
        for (int ksl = 0; ksl < 2; ksl++) {
            short8 af[8], bfv[4];
            #pragma unroll
            for (int mf = 0; mf < 8; mf++) {
                const int row = wr * 128 + mf * 16 + r16;
                af[mf] = *(const short8*)(sBb + row * 128 + (((ksl * 4 + g) ^ (row & 7)) << 4));
            }
            #pragma unroll
            for (int nf = 0; nf < 4; nf++) {
                const int row = wc * 64 + nf * 16 + r16;
                bfv[nf] = *(const short8*)(sAb + row * 128 + (((ksl * 4 + g) ^ (row & 7)) << 4));
            }
            __builtin_amdgcn_s_setprio(1);
            #pragma unroll
            for (int mf = 0; mf < 8; mf++)
                #pragma unroll
                for (int nf = 0; nf < 4; nf++)
                    acc[mf][nf] = __builtin_amdgcn_mfma_f32_16x16x32_bf16(af[mf], bfv[nf], acc[mf][nf], 0, 0, 0);
            __builtin_amdgcn_s_setprio(0);
        }
    }

    // store O: R = (bi*32+bj)*64 + p; ck = ((nf&1)*16+r16)*32 + (mf&1)*16 + g*4
    const size_t Rb = ((size_t)bi * 32 + bj) * 64;
    #pragma unroll
    for (int nf = 0; nf < 4; nf++) {
        #pragma unroll
        for (int mf = 0; mf < 8; mf++) {
            const int p   = (wc * 2 + (nf >> 1)) * 8 + wr * 4 + (mf >> 1);
            const int ck0 = ((nf & 1) * 16 + r16) * 32 + (mf & 1) * 16 + g * 4;
            short4v v;
            v.x = f2bf(acc[mf][nf][0]); v.y = f2bf(acc[mf][nf][1]);
            v.z = f2bf(acc[mf][nf][2]); v.w = f2bf(acc[mf][nf][3]);
            *(short4v*)&gO[(Rb + p) * 1024 + ck0] = v;
        }
    }
}

// ================= PATH 2, Kernel B: Z[65536][128] = O @ WoutT^T, K=1024 ====================
// 512 blocks x 128 rows, 512 thr (8 waves = 2wr x 4wc: 64 rows x 32 z each).
// A-chunks [128 rows][128 ck] 32KB dbuf via gload_lds (swizzled source);
// W register-rolled 1 chunk ahead; counted vmcnt(12); fully unrolled.
__global__ __launch_bounds__(512, 2) void k_gemmB(const short* __restrict__ gO,
                                                  const __hip_bfloat16* __restrict__ WoutT,
                                                  const float* __restrict__ bout,
                                                  float* __restrict__ out) {
    const int t = threadIdx.x, lane = t & 63, wid = t >> 6;
    const int g = lane >> 4, r16 = lane & 15;
    const int wr = wid >> 2, wc = wid & 3;           // wr: row half (64), wc: z quarter (32)
    const size_t R0 = (size_t)blockIdx.x * 128;
    const short* wtW = (const short*)WoutT;
    const int z0 = wc * 32 + r16;
    const int z1 = wc * 32 + 16 + r16;

    #define STAGEC(c, b)                                                                 \
        {                                                                                \
            _Pragma("unroll")                                                            \
            for (int i = 0; i < 4; i++) {                                                \
                const int row = i * 32 + wid * 4 + (lane >> 4);                          \
                const int sg  = lane & 15;                                               \
                const int ssg = (sg & 8) | ((sg & 7) ^ (row & 7));                       \
                stage16(gO + (R0 + row) * 1024 + (c) * 128 + ssg * 8,                    \
                        lds + (b) * 32768 + i * 8192 + wid * 1024);                      \
            }                                                                            \
        }

    #define WLOADC(B, c)                                                                 \
        {                                                                                \
            _Pragma("unroll")                                                            \
            for (int ks = 0; ks < 4; ks++) {                                             \
                B[ks]     = *(const short8*)&wtW[z0 * 1024 + (c) * 128 + ks * 32 + g * 8]; \
                B[4 + ks] = *(const short8*)&wtW[z1 * 1024 + (c) * 128 + ks * 32 + g * 8]; \
            }                                                                            \
        }

    #define COMPC(b, B)                                                                  \
        {                                                                                \
            _Pragma("unroll")                                                            \
            for (int ks = 0; ks < 4; ks++) {                                             \
                short8 av[4];                                                            \
                _Pragma("unroll")                                                        \
                for (int mf = 0; mf < 4; mf++) {                                         \
                    const int row = wr * 64 + mf * 16 + r16;                             \
                    const int gr  = ks * 4 + g;                                          \
                    const int swz = (gr & 8) | ((gr & 7) ^ (row & 7));                   \
                    av[mf] = *(const short8*)(lds + (b) * 32768 + row * 256 + swz * 16); \
                }                                                                        \
                __builtin_amdgcn_s_setprio(1);                                           \
                _Pragma("unroll")                                                        \
                for (int mf = 0; mf < 4; mf++) {                                         \
                    acc[mf][0] = __builtin_amdgcn_mfma_f32_16x16x32_bf16(av[mf], B[ks],     acc[mf][0], 0, 0, 0); \
                    acc[mf][1] = __builtin_amdgcn_mfma_f32_16x16x32_bf16(av[mf], B[4 + ks], acc[mf][1], 0, 0, 0); \
                }                                                                        \
                __builtin_amdgcn_s_setprio(0);                                           \
            }                                                                            \
        }

    #define CH(c, b, WC, WN, LAST)                                                       \
        {                                                                                \
            if (!(LAST)) { STAGEC((c) + 1, 1 - (b)) WLOADC(WN, (c) + 1) }                \
            if (LAST) { asm volatile("s_waitcnt vmcnt(0)" ::: "memory"); }               \
            else      { asm volatile("s_waitcnt vmcnt(12)" ::: "memory"); }              \
            __builtin_amdgcn_s_barrier();                                                \
            COMPC(b, WC)                                                                 \
            __builtin_amdgcn_s_barrier();                                                \
        }

    short8 W0[8], W1[8];
    STAGEC(0, 0)
    WLOADC(W0, 0)

    const float bv0 = bout[z0];
    const float bv1 = bout[z1];
    f32x4 acc[4][2];
    #pragma unroll
    for (int mf = 0; mf < 4; mf++) {
        acc[mf][0] = (f32x4){bv0, bv0, bv0, bv0};
        acc[mf][1] = (f32x4){bv1, bv1, bv1, bv1};
    }

    CH(0, 0, W0, W1, 0) CH(1, 1, W1, W0, 0) CH(2, 0, W0, W1, 0) CH(3, 1, W1, W0, 0)
    CH(4, 0, W0, W1, 0) CH(5, 1, W1, W0, 0) CH(6, 0, W0, W1, 0) CH(7, 1, W1, W0, 1)

    #pragma unroll
    for (int mf = 0; mf < 4; mf++) {
        #pragma unroll
        for (int reg = 0; reg < 4; reg++) {
            const size_t R = R0 + wr * 64 + mf * 16 + g * 4 + reg;
            const int tile = (int)(R >> 6), p = (int)(R & 63);
            const int ig = (tile >> 5) * 8 + (p >> 3);
            const int jg = (tile & 31) * 8 + (p & 7);
            const size_t ob = ((size_t)(ig * 256 + jg)) * 128;
            out[ob + z0] = acc[mf][0][reg] * (1.f / 128.f);
            out[ob + z1] = acc[mf][1][reg] * (1.f / 128.f);
        }
    }
    #undef STAGEC
    #undef WLOADC
    #undef COMPC
    #undef CH
}

// ================= PATH 1 fallback: fused k_gemm6 (verbatim R6, 57.6us) =====================
__global__ __launch_bounds__(512, 1) void k_gemm6(const __hip_bfloat16* __restrict__ Apb,
                                                  const __hip_bfloat16* __restrict__ Bpb,
                                                  const __hip_bfloat16* __restrict__ WoutT,
                                                  const float* __restrict__ bout,
                                                  float* __restrict__ out) {
    const int t = threadIdx.x, lane = t & 63, wid = t >> 6;
    const int g = lane >> 4, r16 = lane & 15;
    const int wr = wid >> 2, wc = wid & 3;
    const int bid = (blockIdx.x & 7) * 128 + (blockIdx.x >> 3);
    const int bi = bid >> 5, bj = bid & 31;

    const short* gA = (const short*)Apb + (size_t)bi * 256 * 128;
    const short* gB = (const short*)Bpb + (size_t)bj * 256 * 128;

    const int srow8 = lane >> 3;
    const int sgran = (lane & 7) ^ srow8;
    #pragma unroll
    for (int kh = 0; kh < 2; kh++) {
        #pragma unroll
        for (int rd = 0; rd < 4; rd++) {
            const int row = rd * 64 + wid * 8 + srow8;
            stage16(gB + row * 128 + kh * 64 + sgran * 8,
                    lds + kh * 65536 + rd * 8192 + wid * 1024);
            stage16(gA + row * 128 + kh * 64 + sgran * 8,
                    lds + kh * 65536 + 32768 + rd * 8192 + wid * 1024);
        }
    }

    asm volatile("s_waitcnt vmcnt(8)" ::: "memory");
    __builtin_amdgcn_s_barrier();

    f32x4 acc[8][4];
    #pragma unroll
    for (int mf = 0; mf < 8; mf++)
        #pragma unroll
        for (int nf = 0; nf < 4; nf++)
            acc[mf][nf] = (f32x4){0.f, 0.f, 0.f, 0.f};

    #pragma unroll
    for (int kh = 0; kh < 2; kh++) {
        if (kh) {
            asm volatile("s_waitcnt vmcnt(0)" ::: "memory");
            __builtin_amdgcn_s_barrier();
        }
        const char* sBb = lds + kh * 65536;
        const char* sAb = lds + kh * 65536 + 32768;
        #pragma unroll
        for (int ksl = 0; ksl < 2; ksl++) {
            short8 af[8], bfv[4];
            #pragma unroll
            for (int mf = 0; mf < 8; mf++) {
                const int row = wr * 128 + mf * 16 + r16;
                af[mf] = *(const short8*)(sBb + row * 128 + (((ksl * 4 + g) ^ (row & 7)) << 4));
            }
            #pragma unroll
            for (int nf = 0; nf < 4; nf++) {
                const int row = wc * 64 + nf * 16 + r16;
                bfv[nf] = *(const short8*)(sAb + row * 128 + (((ksl * 4 + g) ^ (row & 7)) << 4));
            }
            __builtin_amdgcn_s_setprio(1);
            #pragma unroll
            for (int mf = 0; mf < 8; mf++)
                #pragma unroll
                for (int nf = 0; nf < 4; nf++)
                    acc[mf][nf] = __builtin_amdgcn_mfma_f32_16x16x32_bf16(af[mf], bfv[nf], acc[mf][nf], 0, 0, 0);
            __builtin_amdgcn_s_setprio(0);
        }
    }
    __builtin_amdgcn_s_barrier();

    const int z = wid * 16 + r16;
    const float bv = bout[z];
    f32x4 acc2[4];
    #pragma unroll
    for (int pf = 0; pf < 4; pf++) acc2[pf] = (f32x4){bv, bv, bv, bv};
    const short* wtz = (const short*)WoutT + z * 1024 + g * 8;

    short8 wA[4], wB[4];

    #define WLOAD(buf, h, grp)                                                           \
        {                                                                                \
            _Pragma("unroll")                                                            \
            for (int q = 0; q < 4; q++)                                                  \
                buf[q] = *(const short8*)&wtz[(h) * 512 + ((grp) * 4 + q) * 32];         \
        }
    #define WCOMP(buf, h, grp)                                                           \
        {                                                                                \
            const char* sPh = lds + (h) * 65536;                                         \
            __builtin_amdgcn_s_setprio(1);                                               \
            _Pragma("unroll")                                                            \
            for (int q = 0; q < 4; q++) {                                                \
                const int L = ((grp) * 4 + q) * 64 + g * 16;                             \
                _Pragma("unroll")                                                        \
                for (int pf = 0; pf < 4; pf++) {                                         \
                    const int row = pf * 16 + r16;                                       \
                    short8 pv = *(const short8*)(sPh + row * 1024 +                      \
                                                 (L ^ ((((L >> 7) ^ row) & 7) << 4)));   \
                    acc2[pf] = __builtin_amdgcn_mfma_f32_16x16x32_bf16(pv, buf[q], acc2[pf], 0, 0, 0); \
                }                                                                        \
            }                                                                            \
            __builtin_amdgcn_s_setprio(0);                                               \
        }
    #define REPACK(h)                                                                    \
        {                                                                                \
            char* sPh = lds + (h) * 65536;                                               \
            _Pragma("unroll")                                                            \
            for (int nq = 0; nq < 2; nq++) {                                             \
                const int nf = (h) + nq * 2;                                             \
                const int p = (wc * 2 + nq) * 8 + wr * 4;                                \
                _Pragma("unroll")                                                        \
                for (int mf = 0; mf < 8; mf++) {                                         \
                    const int pp = p + (mf >> 1);                                        \
                    const int L = r16 * 64 + (mf & 1) * 32 + g * 8;                      \
                    short4v v;                                                           \
                    v.x = f2bf(acc[mf][nf][0]); v.y = f2bf(acc[mf][nf][1]);              \
                    v.z = f2bf(acc[mf][nf][2]); v.w = f2bf(acc[mf][nf][3]);              \
                    *(short4v*)(sPh + pp * 1024 + (L ^ ((((L >> 7) ^ pp) & 7) << 4))) = v; \
                }                                                                        \
            }                                                                            \
        }

    WLOAD(wA, 0, 0)
    WLOAD(wB, 0, 1)
    REPACK(0)
    asm volatile("s_waitcnt lgkmcnt(0)" ::: "memory");
    __builtin_amdgcn_s_barrier();
    REPACK(1)

    WCOMP(wA, 0, 0) WLOAD(wA, 0, 2)
    WCOMP(wB, 0, 1) WLOAD(wB, 0, 3)
    WCOMP(wA, 0, 2) WLOAD(wA, 1, 0)
    WCOMP(wB, 0, 3) WLOAD(wB, 1, 1)

    asm volatile("s_waitcnt lgkmcnt(0)" ::: "memory");
    __builtin_amdgcn_s_barrier();

    WCOMP(wA, 1, 0) WLOAD(wA, 1, 2)
    WCOMP(wB, 1, 1) WLOAD(wB, 1, 3)
    WCOMP(wA, 1, 2)
    WCOMP(wB, 1, 3)

    #pragma unroll
    for (int pf = 0; pf < 4; pf++) {
        #pragma unroll
        for (int reg = 0; reg < 4; reg++) {
            const int p = pf * 16 + g * 4 + reg;
            const int ig = bi * 8 + (p >> 3), jg = bj * 8 + (p & 7);
            out[((size_t)(ig * 256 + jg)) * 128 + z] = acc2[pf][reg] * (1.f / 128.f);
        }
    }
    #undef REPACK
    #undef WLOAD
    #undef WCOMP
}

extern "C" void kernel_launch(void* const* d_in, const int* in_sizes, int n_in,
                              void* d_out, int out_size, void* d_ws, size_t ws_size,
                              hipStream_t stream) {
    const float* mm    = (const float*)d_in[0];
    const float* gamma = (const float*)d_in[1];
    const float* beta  = (const float*)d_in[2];
    const float* W1    = (const float*)d_in[3];
    const float* b1    = (const float*)d_in[4];
    const float* W2    = (const float*)d_in[5];
    const float* b2    = (const float*)d_in[6];
    const float* Wout  = (const float*)d_in[7];
    const float* bout  = (const float*)d_in[8];

    __hip_bfloat16* Ap    = (__hip_bfloat16*)((char*)d_ws + WS_A);
    __hip_bfloat16* Bp    = (__hip_bfloat16*)((char*)d_ws + WS_B);
    __hip_bfloat16* WoutT = (__hip_bfloat16*)((char*)d_ws + WS_WT);
    __hip_bfloat16* W12bf = (__hip_bfloat16*)((char*)d_ws + WS_W12);
    short*          gO    = (short*)((char*)d_ws + WS_O);
    float* out = (float*)d_out;

    (void)hipFuncSetAttribute(reinterpret_cast<const void*>(k_gemmA),
                              hipFuncAttributeMaxDynamicSharedMemorySize, 131072);
    (void)hipFuncSetAttribute(reinterpret_cast<const void*>(k_gemmB),
                              hipFuncAttributeMaxDynamicSharedMemorySize, 65536);
    (void)hipFuncSetAttribute(reinterpret_cast<const void*>(k_gemm6),
                              hipFuncAttributeMaxDynamicSharedMemorySize, 131072);

    hipLaunchKernelGGL(k_prep, dim3(576), dim3(256), 0, stream, Wout, W1, W2, WoutT, W12bf);
    hipLaunchKernelGGL(k_lnproj, dim3(512), dim3(256), 0, stream,
                       mm, gamma, beta, b1, b2, W12bf, Ap, Bp);

    const bool big_ws = (ws_size >= (size_t)WS_O + WS_O_BYTES);
    if (big_ws) {
        hipLaunchKernelGGL(k_gemmA, dim3(1024), dim3(512), 131072, stream, Ap, Bp, gO);
        hipLaunchKernelGGL(k_gemmB, dim3(512), dim3(512), 65536, stream,
                           gO, WoutT, bout, out);
    } else {
        hipLaunchKernelGGL(k_gemm6, dim3(1024), dim3(512), 131072, stream,
                           Ap, Bp, WoutT, bout, out);
    }
}